// Round 6
// baseline (2903.757 us; speedup 1.0000x reference)
//
#include <hip/hip_runtime.h>
#include <math.h>

#define B_  2
#define T_  4096
#define D_  1024
#define H_  16
#define BH_ 32
#define NCHUNK_ 64   // T/64

__device__ __forceinline__ float dpp_xor1_add(float v) {
  int s = __builtin_amdgcn_update_dpp(0, __float_as_int(v), 0xB1, 0xF, 0xF, true);
  return v + __int_as_float(s);
}
__device__ __forceinline__ float dpp_xor2_add(float v) {
  int s = __builtin_amdgcn_update_dpp(0, __float_as_int(v), 0x4E, 0xF, 0xF, true);
  return v + __int_as_float(s);
}
__device__ __forceinline__ float dot4(float4 a, float4 b) {
  return fmaf(a.x, b.x, fmaf(a.y, b.y, fmaf(a.z, b.z, a.w * b.w)));
}

// ---------------------------------------------------------------------------
// Generic f32 tiled GEMM (validated): BM=128,BN=128,BK=16, 8x8/thr.
// ---------------------------------------------------------------------------
template<int ACT>
__global__ __launch_bounds__(256) void gemm_f32(const float* __restrict__ A,
    const float* __restrict__ Bm, float* __restrict__ C, int M, int N, int K)
{
  __shared__ float As[16][128];
  __shared__ float Bs[16][128];
  const int bm  = blockIdx.y * 128;
  const int bn  = blockIdx.x * 128;
  const int tid = threadIdx.x;
  const int tx  = tid & 15;
  const int ty  = tid >> 4;
  float acc[8][8];
  #pragma unroll
  for (int i = 0; i < 8; ++i)
    #pragma unroll
    for (int j = 0; j < 8; ++j) acc[i][j] = 0.f;
  const int r  = tid >> 2;
  const int kq = (tid & 3) * 4;
  const int bk = tid >> 4;
  const int nq = (tid & 15) * 8;
  for (int k0 = 0; k0 < K; k0 += 16) {
    float4 a0 = *(const float4*)(A + (size_t)(bm + r)      * K + k0 + kq);
    float4 a1 = *(const float4*)(A + (size_t)(bm + 64 + r) * K + k0 + kq);
    As[kq+0][r]    = a0.x; As[kq+1][r]    = a0.y; As[kq+2][r]    = a0.z; As[kq+3][r]    = a0.w;
    As[kq+0][64+r] = a1.x; As[kq+1][64+r] = a1.y; As[kq+2][64+r] = a1.z; As[kq+3][64+r] = a1.w;
    *(float4*)&Bs[bk][nq]   = *(const float4*)(Bm + (size_t)(k0 + bk) * N + bn + nq);
    *(float4*)&Bs[bk][nq+4] = *(const float4*)(Bm + (size_t)(k0 + bk) * N + bn + nq + 4);
    __syncthreads();
    #pragma unroll
    for (int kk = 0; kk < 16; ++kk) {
      float a[8], b[8];
      *(float4*)&a[0] = *(float4*)&As[kk][ty*8];
      *(float4*)&a[4] = *(float4*)&As[kk][ty*8+4];
      *(float4*)&b[0] = *(float4*)&Bs[kk][tx*8];
      *(float4*)&b[4] = *(float4*)&Bs[kk][tx*8+4];
      #pragma unroll
      for (int i = 0; i < 8; ++i)
        #pragma unroll
        for (int j = 0; j < 8; ++j)
          acc[i][j] = fmaf(a[i], b[j], acc[i][j]);
    }
    __syncthreads();
  }
  #pragma unroll
  for (int i = 0; i < 8; ++i) {
    float o[8];
    #pragma unroll
    for (int j = 0; j < 8; ++j) {
      float v = acc[i][j];
      if (ACT == 1)      v = v / (1.f + __expf(-v));
      else if (ACT == 2) v = 1.f / (1.f + __expf(-v));
      o[j] = v;
    }
    float* cp = C + (size_t)(bm + ty*8 + i) * N + bn + tx*8;
    *(float4*)cp       = *(float4*)&o[0];
    *(float4*)(cp + 4) = *(float4*)&o[4];
  }
}

// ---------------------------------------------------------------------------
// Causal depthwise conv (K=4) + bias + SiLU, heads [BH,T,64], optional L2N.
// ---------------------------------------------------------------------------
template<bool L2N>
__global__ __launch_bounds__(64) void conv_head(const float* __restrict__ xin,
    const float* __restrict__ w, const float* __restrict__ bias,
    float* __restrict__ out)
{
  const int bh = blockIdx.y;
  const int b  = bh >> 4, h = bh & 15;
  const int t0 = blockIdx.x * 16;
  const int c  = threadIdx.x;
  const int ch = h*64 + c;
  const float w0 = w[ch*4+0], w1 = w[ch*4+1], w2 = w[ch*4+2], w3 = w[ch*4+3];
  const float bs = bias[ch];
  const float* xp = xin + ((size_t)b*T_ + t0)*D_ + ch;
  float xm3 = (t0 >= 3) ? xp[-3*D_] : 0.f;
  float xm2 = (t0 >= 2) ? xp[-2*D_] : 0.f;
  float xm1 = (t0 >= 1) ? xp[-1*D_] : 0.f;
  float* op = out + ((size_t)bh*T_ + t0)*64 + c;
  for (int tt = 0; tt < 16; ++tt) {
    float xc = xp[(size_t)tt * D_];
    float v  = fmaf(w0, xm3, fmaf(w1, xm2, fmaf(w2, xm1, fmaf(w3, xc, bs))));
    v = v / (1.f + __expf(-v));
    if (L2N) {
      float ss = v*v;
      #pragma unroll
      for (int off = 32; off > 0; off >>= 1) ss += __shfl_xor(ss, off, 64);
      v = v / fmaxf(sqrtf(ss), 1e-6f);
    }
    op[tt*64] = v;
    xm3 = xm2; xm2 = xm1; xm1 = xc;
  }
}

// ---------------------------------------------------------------------------
// alpha/beta gates (unchanged)
// ---------------------------------------------------------------------------
__global__ __launch_bounds__(256) void ab_kernel(const float* __restrict__ x,
    const float* __restrict__ Wa, const float* __restrict__ ba,
    const float* __restrict__ Wb, const float* __restrict__ bb,
    float* __restrict__ alpha, float* __restrict__ beta)
{
  __shared__ float xs[1024];
  const int rrow = blockIdx.x;
  const int b = rrow >> 12, t = rrow & 4095;
  const int tid = threadIdx.x;
  ((float4*)xs)[tid] = ((const float4*)(x + (size_t)rrow * D_))[tid];
  __syncthreads();
  const int out = tid >> 3;
  const int s   = tid & 7;
  const bool isB = out >= 16;
  const int h = out & 15;
  const float* W = isB ? Wb : Wa;
  float acc = 0.f;
  #pragma unroll 8
  for (int m = 0; m < 128; ++m) {
    int kidx = m*8 + s;
    acc = fmaf(xs[kidx], W[kidx*16 + h], acc);
  }
  acc += __shfl_xor(acc, 1, 64);
  acc += __shfl_xor(acc, 2, 64);
  acc += __shfl_xor(acc, 4, 64);
  if (s == 0) {
    float bias = isB ? bb[h] : ba[h];
    float sg = 1.f / (1.f + __expf(-(acc + bias)));
    int bh = b*16 + h;
    if (isB) beta [(size_t)bh*T_ + t] = fminf(sg, 1.0f);
    else     alpha[(size_t)bh*T_ + t] = fminf(fmaxf(sg, 0.1f), 1.0f);
  }
}

// ---------------------------------------------------------------------------
// CHUNKED DELTA RULE — precompute, parallel over 2048 (head,chunk) blocks.
// IN-PLACE to save workspace:  QS -> Q rows, errA -> V rows, WKT -> K rows.
// Att+U go to attU[bhc][8192] (Att at +0, U at +4096).
// ---------------------------------------------------------------------------
__global__ __launch_bounds__(256) void precompute_chunks(
    float* Kglob,            // in: K rows, out: WKT rows (chunk-local)
    float* Qglob,            // in: Q rows, out: QS rows (chunk-local)
    float* VAglob,           // in: V rows, out: errA rows (chunk-local)
    const float* __restrict__ alpha, const float* __restrict__ beta,
    float* __restrict__ attU, float* __restrict__ plast)
{
  __shared__ float Ks[64][68];   // padded
  __shared__ float XVs[64][64];  // Q staging, then solve RHS/solution
  __shared__ float Ms[64][64];
  __shared__ float Gs[64], bv[64];
  const int bhc = blockIdx.x;
  const int bh  = bhc >> 6, c = bhc & 63;
  const int tid = threadIdx.x;
  const size_t rowbase = ((size_t)bh * T_ + c * 64) * 64;
  float* Kb = Kglob + rowbase;
  float* Qb = Qglob + rowbase;
  float* Vb = VAglob + rowbase;
  float* attG = attU + (size_t)bhc * 8192;
  float* uG   = attG + 4096;

  // stage K (padded LDS) and Q (into XVs)
  for (int u = tid; u < 1024; u += 256) {
    int f = u * 4; int row = f >> 6; int col = f & 63;
    *(float4*)&Ks[row][col]  = *(const float4*)(Kb + f);
    *(float4*)&XVs[row][col] = *(const float4*)(Qb + f);
  }
  if (tid < 64) {
    bv[tid] = beta[(size_t)bh*T_ + c*64 + tid];
    float xv = __logf(alpha[(size_t)bh*T_ + c*64 + tid]);
    #pragma unroll
    for (int off = 1; off < 64; off <<= 1) {
      float n = __shfl_up(xv, off, 64);
      if (tid >= off) xv += n;
    }
    Gs[tid] = xv;
  }
  __syncthreads();

  const int j0 = tid & 15;            // strided j
  const int i4 = (tid >> 4) * 4;      // 4 consecutive i
  // KK & QK GEMMs (dot over d)
  float accK[4][4], accQ[4][4];
  #pragma unroll
  for (int s = 0; s < 4; ++s)
    #pragma unroll
    for (int t = 0; t < 4; ++t) { accK[s][t] = 0.f; accQ[s][t] = 0.f; }
  for (int db = 0; db < 64; db += 4) {
    float4 ki[4], qi[4], kj[4];
    #pragma unroll
    for (int s = 0; s < 4; ++s) {
      ki[s] = *(float4*)&Ks[i4+s][db];
      qi[s] = *(float4*)&XVs[i4+s][db];
    }
    #pragma unroll
    for (int t = 0; t < 4; ++t) kj[t] = *(float4*)&Ks[j0+16*t][db];
    #pragma unroll
    for (int s = 0; s < 4; ++s)
      #pragma unroll
      for (int t = 0; t < 4; ++t) {
        accK[s][t] += dot4(ki[s], kj[t]);
        accQ[s][t] += dot4(qi[s], kj[t]);
      }
  }
  const float G63 = Gs[63];
  #pragma unroll
  for (int s = 0; s < 4; ++s) {
    int i = i4 + s;
    float Gi = Gs[i];
    float Gim1 = (i > 0) ? Gs[i-1] : 0.f;
    #pragma unroll
    for (int t = 0; t < 4; ++t) {
      int j = j0 + 16*t;
      float bj = bv[j], Gj = Gs[j];
      Ms[i][j] = (j < i) ? __expf(Gim1 - Gj) * bj * accK[s][t] : 0.f;
      attG[i*64 + j] = (j <= i) ? __expf(Gi - Gj) * bj * accQ[s][t] : 0.f;
    }
  }
  // QS write-back in place (Q still lives in XVs)
  for (int u = tid; u < 1024; u += 256) {
    int f = u * 4; int row = f >> 6; int col = f & 63;
    float pf = __expf(Gs[row]);
    float4 q = *(float4*)&XVs[row][col];
    q.x *= pf; q.y *= pf; q.z *= pf; q.w *= pf;
    *(float4*)(Qb + f) = q;
  }
  __syncthreads();

  // two forward-substitution solves: pass0 errA (RHS=V) -> V rows,
  // pass1 U (RHS=Pprev*K) -> attU+4096.
  const int sc = tid >> 2, hh = tid & 3;
  for (int pass = 0; pass < 2; ++pass) {
    for (int u = tid; u < 1024; u += 256) {
      int f = u * 4; int row = f >> 6; int col = f & 63;
      if (pass == 0) {
        *(float4*)&XVs[row][col] = *(const float4*)(Vb + f);
      } else {
        float pp = __expf((row > 0) ? Gs[row-1] : 0.f);
        float4 k = *(float4*)&Ks[row][col];
        k.x *= pp; k.y *= pp; k.z *= pp; k.w *= pp;
        *(float4*)&XVs[row][col] = k;
      }
    }
    __syncthreads();
    for (int i = 1; i < 64; ++i) {
      float sum = 0.f;
      int jlo = hh * 16;
      int jhi = min(i, jlo + 16);
      for (int j = jlo; j < jhi; ++j) sum = fmaf(Ms[i][j], XVs[j][sc], sum);
      sum = dpp_xor1_add(sum);
      sum = dpp_xor2_add(sum);
      if (hh == 0) XVs[i][sc] -= sum;
      __syncthreads();
    }
    float* dst = (pass == 0) ? Vb : uG;
    for (int u = tid; u < 1024; u += 256) {
      int f = u * 4; int row = f >> 6; int col = f & 63;
      *(float4*)(dst + f) = *(float4*)&XVs[row][col];
    }
    __syncthreads();
  }
  // WKT[r][j] = exp(G63-Gj)*b_j*K[j][r]  -> written into K's rows (staged)
  #pragma unroll
  for (int s = 0; s < 4; ++s) {
    int rr = i4 + s;
    #pragma unroll
    for (int t = 0; t < 4; ++t) {
      int j = j0 + 16*t;
      Kb[rr*64 + j] = __expf(G63 - Gs[j]) * bv[j] * Ks[j][rr];
    }
  }
  if (tid == 0) plast[bhc] = __expf(G63);
}

// ---------------------------------------------------------------------------
// CHUNKED DELTA RULE — serial kernel. 32 blocks (1/head), 256 threads.
// Per chunk: err = errA - U@S0 ; O = QS@S0 + Att@err ; S0 <- pl*S0 + WKT@err.
// EO: errA in / O out (same rows, read-before-write within the block).
// WKTg = K rows (in-place from precompute). Qs = QS rows.
// ---------------------------------------------------------------------------
__global__ __launch_bounds__(256) void scan_chunks(
    const float* __restrict__ attU, const float* __restrict__ WKTg,
    const float* __restrict__ QSg, const float* __restrict__ plast,
    float* EO)
{
  __shared__ float S0T[64][68];
  __shared__ float errT[64][68];
  const int bh  = blockIdx.x;
  const int tid = threadIdx.x;
  const int n0  = tid & 15;
  const int i4  = (tid >> 4) * 4;
  for (int u = tid; u < 64*68; u += 256) ((float*)S0T)[u] = 0.f;
  __syncthreads();

  for (int c = 0; c < NCHUNK_; ++c) {
    const size_t rowb = ((size_t)bh * T_ + c * 64) * 64;
    const float* Aa = attU + (size_t)(bh*64 + c) * 8192;
    const float* Ua = Aa + 4096;
    const float* Ea = EO + rowb;
    const float* Wk = WKTg + rowb;
    const float* Qs = QSg + rowb;
    const float  pl = plast[bh*64 + c];

    // GEMM1: err[i][n] = Ea[i][n] - sum_j Ua[i][j] * S0[j][n]
    float acc[4][4];
    #pragma unroll
    for (int s = 0; s < 4; ++s)
      #pragma unroll
      for (int t = 0; t < 4; ++t) acc[s][t] = Ea[(i4+s)*64 + n0 + 16*t];
    for (int jb = 0; jb < 64; jb += 4) {
      float4 uu[4], ss[4];
      #pragma unroll
      for (int s = 0; s < 4; ++s) uu[s] = *(const float4*)(Ua + (i4+s)*64 + jb);
      #pragma unroll
      for (int t = 0; t < 4; ++t) ss[t] = *(float4*)&S0T[n0+16*t][jb];
      #pragma unroll
      for (int s = 0; s < 4; ++s)
        #pragma unroll
        for (int t = 0; t < 4; ++t) acc[s][t] -= dot4(uu[s], ss[t]);
    }
    #pragma unroll
    for (int t = 0; t < 4; ++t) {
      float4 w; w.x = acc[0][t]; w.y = acc[1][t]; w.z = acc[2][t]; w.w = acc[3][t];
      *(float4*)&errT[n0+16*t][i4] = w;
    }
    __syncthreads();

    // GEMM2: O[i][n] = sum_r QS[i][r]*S0[r][n] + sum_j Att[i][j]*err[j][n]
    // GEMM3: Snew[r][n] = pl*S0[r][n] + sum_j WKT[r][j]*err[j][n]
    float acco[4][4], accs[4][4];
    #pragma unroll
    for (int s = 0; s < 4; ++s)
      #pragma unroll
      for (int t = 0; t < 4; ++t) {
        acco[s][t] = 0.f;
        accs[s][t] = pl * S0T[n0+16*t][i4+s];
      }
    for (int rb = 0; rb < 64; rb += 4) {
      float4 qq[4], ss[4];
      #pragma unroll
      for (int s = 0; s < 4; ++s) qq[s] = *(const float4*)(Qs + (i4+s)*64 + rb);
      #pragma unroll
      for (int t = 0; t < 4; ++t) ss[t] = *(float4*)&S0T[n0+16*t][rb];
      #pragma unroll
      for (int s = 0; s < 4; ++s)
        #pragma unroll
        for (int t = 0; t < 4; ++t) acco[s][t] += dot4(qq[s], ss[t]);
    }
    for (int jb = 0; jb < 64; jb += 4) {
      float4 aa[4], ww[4], ee[4];
      #pragma unroll
      for (int s = 0; s < 4; ++s) {
        aa[s] = *(const float4*)(Aa + (i4+s)*64 + jb);
        ww[s] = *(const float4*)(Wk + (i4+s)*64 + jb);
      }
      #pragma unroll
      for (int t = 0; t < 4; ++t) ee[t] = *(float4*)&errT[n0+16*t][jb];
      #pragma unroll
      for (int s = 0; s < 4; ++s)
        #pragma unroll
        for (int t = 0; t < 4; ++t) {
          acco[s][t] += dot4(aa[s], ee[t]);
          accs[s][t] += dot4(ww[s], ee[t]);
        }
    }
    // store O (overwrites errA rows — all Ea reads completed above)
    float* Ob = EO + rowb;
    #pragma unroll
    for (int s = 0; s < 4; ++s)
      #pragma unroll
      for (int t = 0; t < 4; ++t) Ob[(i4+s)*64 + n0 + 16*t] = acco[s][t];
    __syncthreads();
    // commit new state
    #pragma unroll
    for (int t = 0; t < 4; ++t) {
      float4 w; w.x = accs[0][t]; w.y = accs[1][t]; w.z = accs[2][t]; w.w = accs[3][t];
      *(float4*)&S0T[n0+16*t][i4] = w;
    }
    __syncthreads();
  }
}

// ---------------------------------------------------------------------------
// Per-head RMSNorm + sigmoid output gate; writes [B,T,H*64].
// ---------------------------------------------------------------------------
__global__ __launch_bounds__(64) void rmsgate(const float* __restrict__ O,
    const float* __restrict__ g, const float* __restrict__ rmsw,
    float* __restrict__ outp)
{
  const int bh = blockIdx.y;
  const int b  = bh >> 4, h = bh & 15;
  const int t0 = blockIdx.x * 16;
  const int c  = threadIdx.x;
  const float rw = rmsw[h*64 + c];
  for (int tt = 0; tt < 16; ++tt) {
    const int t = t0 + tt;
    float o  = O[((size_t)bh*T_ + t)*64 + c];
    float ss = o*o;
    #pragma unroll
    for (int off = 32; off > 0; off >>= 1) ss += __shfl_xor(ss, off, 64);
    float r   = rsqrtf(ss * (1.f/64.f) + 1e-6f);
    float val = o * r * rw * g[((size_t)b*T_ + t)*D_ + h*64 + c];
    outp[((size_t)b*T_ + t)*D_ + h*64 + c] = val;
  }
}

// ---------------------------------------------------------------------------
// Workspace (floats):
//   linbuf 8M | Qh 8M | Kk 8M | Vv 8M | attU 16.78M (g1 aliases first 4M)
//   alpha 128K | beta 128K | plast 2K         total ~49.1M floats ~196 MB
// In-place: QS->Qh, errA->Vv, WKT->Kk, O->Vv, gated->Kk.
// ---------------------------------------------------------------------------
extern "C" void kernel_launch(void* const* d_in, const int* in_sizes, int n_in,
                              void* d_out, int out_size, void* d_ws, size_t ws_size,
                              hipStream_t stream)
{
  const float* x    = (const float*)d_in[0];
  const float* Wq   = (const float*)d_in[1];
  const float* Wk   = (const float*)d_in[2];
  const float* Wv   = (const float*)d_in[3];
  const float* Wo   = (const float*)d_in[4];
  const float* Wa   = (const float*)d_in[5];
  const float* ba   = (const float*)d_in[6];
  const float* Wb   = (const float*)d_in[7];
  const float* bb   = (const float*)d_in[8];
  const float* Wgd  = (const float*)d_in[9];
  const float* Wgu  = (const float*)d_in[10];
  const float* rmsw = (const float*)d_in[11];
  const float* qcw  = (const float*)d_in[12];
  const float* qcb  = (const float*)d_in[13];
  const float* kcw  = (const float*)d_in[14];
  const float* kcb  = (const float*)d_in[15];
  const float* vcw  = (const float*)d_in[16];
  const float* vcb  = (const float*)d_in[17];

  float* ws = (float*)d_ws;
  const size_t S0sz = (size_t)8192 * 1024;
  float* linbuf = ws;                    // staging / later g
  float* Qh     = ws + S0sz;             // Q then QS
  float* Kk     = ws + 2*S0sz;           // K then WKT, then gated
  float* Vv     = ws + 3*S0sz;           // V then errA then O
  float* attU   = ws + 4*S0sz;           // [2048][8192]; g1 aliases first 4M
  float* g1     = attU;                  // [8192,512] (dead before precompute)
  float* alpha  = attU + (size_t)2048*8192;
  float* beta   = alpha + (size_t)BH_ * T_;
  float* plast  = beta + (size_t)BH_ * T_;

  const dim3 blk256(256);
  const dim3 gBig(8, 64);
  const dim3 gMid(4, 64);

  gemm_f32<0><<<gBig, blk256, 0, stream>>>(x, Wq, linbuf, 8192, 1024, 1024);
  conv_head<true ><<<dim3(T_/16, BH_), 64, 0, stream>>>(linbuf, qcw, qcb, Qh);
  gemm_f32<0><<<gBig, blk256, 0, stream>>>(x, Wk, linbuf, 8192, 1024, 1024);
  conv_head<true ><<<dim3(T_/16, BH_), 64, 0, stream>>>(linbuf, kcw, kcb, Kk);
  gemm_f32<0><<<gBig, blk256, 0, stream>>>(x, Wv, linbuf, 8192, 1024, 1024);
  conv_head<false><<<dim3(T_/16, BH_), 64, 0, stream>>>(linbuf, vcw, vcb, Vv);
  ab_kernel<<<8192, blk256, 0, stream>>>(x, Wa, ba, Wb, bb, alpha, beta);
  gemm_f32<1><<<gMid, blk256, 0, stream>>>(x, Wgd, g1, 8192, 512, 1024);
  float* g = linbuf;  // linbuf dead after conv v
  gemm_f32<2><<<gBig, blk256, 0, stream>>>(g1, Wgu, g, 8192, 1024, 512);

  // chunked delta rule: parallel precompute (in-place) + short serial chain
  precompute_chunks<<<BH_ * NCHUNK_, blk256, 0, stream>>>(Kk, Qh, Vv, alpha, beta,
                                                          attU, plast);
  scan_chunks<<<BH_, blk256, 0, stream>>>(attU, Kk, Qh, plast, Vv);

  float* gated = Kk;  // WKT dead after scan
  rmsgate<<<dim3(T_/16, BH_), 64, 0, stream>>>(Vv, g, rmsw, gated);
  gemm_f32<0><<<gBig, blk256, 0, stream>>>(gated, Wo, (float*)d_out, 8192, 1024, 1024);
}

// Round 7
// 2215.900 us; speedup vs baseline: 1.3104x; 1.3104x over previous
//
#include <hip/hip_runtime.h>
#include <math.h>

#define B_  2
#define T_  4096
#define D_  1024
#define H_  16
#define BH_ 32
#define NCHUNK_ 64   // T/64

__device__ __forceinline__ float dpp_xor1_add(float v) {
  int s = __builtin_amdgcn_update_dpp(0, __float_as_int(v), 0xB1, 0xF, 0xF, true);
  return v + __int_as_float(s);
}
__device__ __forceinline__ float dpp_xor2_add(float v) {
  int s = __builtin_amdgcn_update_dpp(0, __float_as_int(v), 0x4E, 0xF, 0xF, true);
  return v + __int_as_float(s);
}
__device__ __forceinline__ float dot4(float4 a, float4 b) {
  return fmaf(a.x, b.x, fmaf(a.y, b.y, fmaf(a.z, b.z, a.w * b.w)));
}

// ---------------------------------------------------------------------------
// Generic f32 tiled GEMM (validated): BM=128,BN=128,BK=16, 8x8/thr.
// ---------------------------------------------------------------------------
template<int ACT>
__global__ __launch_bounds__(256) void gemm_f32(const float* __restrict__ A,
    const float* __restrict__ Bm, float* __restrict__ C, int M, int N, int K)
{
  __shared__ float As[16][128];
  __shared__ float Bs[16][128];
  const int bm  = blockIdx.y * 128;
  const int bn  = blockIdx.x * 128;
  const int tid = threadIdx.x;
  const int tx  = tid & 15;
  const int ty  = tid >> 4;
  float acc[8][8];
  #pragma unroll
  for (int i = 0; i < 8; ++i)
    #pragma unroll
    for (int j = 0; j < 8; ++j) acc[i][j] = 0.f;
  const int r  = tid >> 2;
  const int kq = (tid & 3) * 4;
  const int bk = tid >> 4;
  const int nq = (tid & 15) * 8;
  for (int k0 = 0; k0 < K; k0 += 16) {
    float4 a0 = *(const float4*)(A + (size_t)(bm + r)      * K + k0 + kq);
    float4 a1 = *(const float4*)(A + (size_t)(bm + 64 + r) * K + k0 + kq);
    As[kq+0][r]    = a0.x; As[kq+1][r]    = a0.y; As[kq+2][r]    = a0.z; As[kq+3][r]    = a0.w;
    As[kq+0][64+r] = a1.x; As[kq+1][64+r] = a1.y; As[kq+2][64+r] = a1.z; As[kq+3][64+r] = a1.w;
    *(float4*)&Bs[bk][nq]   = *(const float4*)(Bm + (size_t)(k0 + bk) * N + bn + nq);
    *(float4*)&Bs[bk][nq+4] = *(const float4*)(Bm + (size_t)(k0 + bk) * N + bn + nq + 4);
    __syncthreads();
    #pragma unroll
    for (int kk = 0; kk < 16; ++kk) {
      float a[8], b[8];
      *(float4*)&a[0] = *(float4*)&As[kk][ty*8];
      *(float4*)&a[4] = *(float4*)&As[kk][ty*8+4];
      *(float4*)&b[0] = *(float4*)&Bs[kk][tx*8];
      *(float4*)&b[4] = *(float4*)&Bs[kk][tx*8+4];
      #pragma unroll
      for (int i = 0; i < 8; ++i)
        #pragma unroll
        for (int j = 0; j < 8; ++j)
          acc[i][j] = fmaf(a[i], b[j], acc[i][j]);
    }
    __syncthreads();
  }
  #pragma unroll
  for (int i = 0; i < 8; ++i) {
    float o[8];
    #pragma unroll
    for (int j = 0; j < 8; ++j) {
      float v = acc[i][j];
      if (ACT == 1)      v = v / (1.f + __expf(-v));
      else if (ACT == 2) v = 1.f / (1.f + __expf(-v));
      o[j] = v;
    }
    float* cp = C + (size_t)(bm + ty*8 + i) * N + bn + tx*8;
    *(float4*)cp       = *(float4*)&o[0];
    *(float4*)(cp + 4) = *(float4*)&o[4];
  }
}

// ---------------------------------------------------------------------------
// Causal depthwise conv (K=4) + bias + SiLU, heads [BH,T,64], optional L2N.
// ---------------------------------------------------------------------------
template<bool L2N>
__global__ __launch_bounds__(64) void conv_head(const float* __restrict__ xin,
    const float* __restrict__ w, const float* __restrict__ bias,
    float* __restrict__ out)
{
  const int bh = blockIdx.y;
  const int b  = bh >> 4, h = bh & 15;
  const int t0 = blockIdx.x * 16;
  const int c  = threadIdx.x;
  const int ch = h*64 + c;
  const float w0 = w[ch*4+0], w1 = w[ch*4+1], w2 = w[ch*4+2], w3 = w[ch*4+3];
  const float bs = bias[ch];
  const float* xp = xin + ((size_t)b*T_ + t0)*D_ + ch;
  float xm3 = (t0 >= 3) ? xp[-3*D_] : 0.f;
  float xm2 = (t0 >= 2) ? xp[-2*D_] : 0.f;
  float xm1 = (t0 >= 1) ? xp[-1*D_] : 0.f;
  float* op = out + ((size_t)bh*T_ + t0)*64 + c;
  for (int tt = 0; tt < 16; ++tt) {
    float xc = xp[(size_t)tt * D_];
    float v  = fmaf(w0, xm3, fmaf(w1, xm2, fmaf(w2, xm1, fmaf(w3, xc, bs))));
    v = v / (1.f + __expf(-v));
    if (L2N) {
      float ss = v*v;
      #pragma unroll
      for (int off = 32; off > 0; off >>= 1) ss += __shfl_xor(ss, off, 64);
      v = v / fmaxf(sqrtf(ss), 1e-6f);
    }
    op[tt*64] = v;
    xm3 = xm2; xm2 = xm1; xm1 = xc;
  }
}

// ---------------------------------------------------------------------------
// alpha/beta gates (unchanged)
// ---------------------------------------------------------------------------
__global__ __launch_bounds__(256) void ab_kernel(const float* __restrict__ x,
    const float* __restrict__ Wa, const float* __restrict__ ba,
    const float* __restrict__ Wb, const float* __restrict__ bb,
    float* __restrict__ alpha, float* __restrict__ beta)
{
  __shared__ float xs[1024];
  const int rrow = blockIdx.x;
  const int b = rrow >> 12, t = rrow & 4095;
  const int tid = threadIdx.x;
  ((float4*)xs)[tid] = ((const float4*)(x + (size_t)rrow * D_))[tid];
  __syncthreads();
  const int out = tid >> 3;
  const int s   = tid & 7;
  const bool isB = out >= 16;
  const int h = out & 15;
  const float* W = isB ? Wb : Wa;
  float acc = 0.f;
  #pragma unroll 8
  for (int m = 0; m < 128; ++m) {
    int kidx = m*8 + s;
    acc = fmaf(xs[kidx], W[kidx*16 + h], acc);
  }
  acc += __shfl_xor(acc, 1, 64);
  acc += __shfl_xor(acc, 2, 64);
  acc += __shfl_xor(acc, 4, 64);
  if (s == 0) {
    float bias = isB ? bb[h] : ba[h];
    float sg = 1.f / (1.f + __expf(-(acc + bias)));
    int bh = b*16 + h;
    if (isB) beta [(size_t)bh*T_ + t] = fminf(sg, 1.0f);
    else     alpha[(size_t)bh*T_ + t] = fminf(fmaxf(sg, 0.1f), 1.0f);
  }
}

// ---------------------------------------------------------------------------
// CHUNKED DELTA RULE — precompute (validated round 6, unchanged).
// Outputs: Att,U -> attU ; errA -> V rows ; WKT -> K rows ; QS -> Q rows.
// ---------------------------------------------------------------------------
__global__ __launch_bounds__(256) void precompute_chunks(
    float* Kglob, float* Qglob, float* VAglob,
    const float* __restrict__ alpha, const float* __restrict__ beta,
    float* __restrict__ attU, float* __restrict__ plast)
{
  __shared__ float Ks[64][68];
  __shared__ float XVs[64][64];
  __shared__ float Ms[64][64];
  __shared__ float Gs[64], bv[64];
  const int bhc = blockIdx.x;
  const int bh  = bhc >> 6, c = bhc & 63;
  const int tid = threadIdx.x;
  const size_t rowbase = ((size_t)bh * T_ + c * 64) * 64;
  float* Kb = Kglob + rowbase;
  float* Qb = Qglob + rowbase;
  float* Vb = VAglob + rowbase;
  float* attG = attU + (size_t)bhc * 8192;
  float* uG   = attG + 4096;

  for (int u = tid; u < 1024; u += 256) {
    int f = u * 4; int row = f >> 6; int col = f & 63;
    *(float4*)&Ks[row][col]  = *(const float4*)(Kb + f);
    *(float4*)&XVs[row][col] = *(const float4*)(Qb + f);
  }
  if (tid < 64) {
    bv[tid] = beta[(size_t)bh*T_ + c*64 + tid];
    float xv = __logf(alpha[(size_t)bh*T_ + c*64 + tid]);
    #pragma unroll
    for (int off = 1; off < 64; off <<= 1) {
      float n = __shfl_up(xv, off, 64);
      if (tid >= off) xv += n;
    }
    Gs[tid] = xv;
  }
  __syncthreads();

  const int j0 = tid & 15;
  const int i4 = (tid >> 4) * 4;
  float accK[4][4], accQ[4][4];
  #pragma unroll
  for (int s = 0; s < 4; ++s)
    #pragma unroll
    for (int t = 0; t < 4; ++t) { accK[s][t] = 0.f; accQ[s][t] = 0.f; }
  for (int db = 0; db < 64; db += 4) {
    float4 ki[4], qi[4], kj[4];
    #pragma unroll
    for (int s = 0; s < 4; ++s) {
      ki[s] = *(float4*)&Ks[i4+s][db];
      qi[s] = *(float4*)&XVs[i4+s][db];
    }
    #pragma unroll
    for (int t = 0; t < 4; ++t) kj[t] = *(float4*)&Ks[j0+16*t][db];
    #pragma unroll
    for (int s = 0; s < 4; ++s)
      #pragma unroll
      for (int t = 0; t < 4; ++t) {
        accK[s][t] += dot4(ki[s], kj[t]);
        accQ[s][t] += dot4(qi[s], kj[t]);
      }
  }
  const float G63 = Gs[63];
  #pragma unroll
  for (int s = 0; s < 4; ++s) {
    int i = i4 + s;
    float Gi = Gs[i];
    float Gim1 = (i > 0) ? Gs[i-1] : 0.f;
    #pragma unroll
    for (int t = 0; t < 4; ++t) {
      int j = j0 + 16*t;
      float bj = bv[j], Gj = Gs[j];
      Ms[i][j] = (j < i) ? __expf(Gim1 - Gj) * bj * accK[s][t] : 0.f;
      attG[i*64 + j] = (j <= i) ? __expf(Gi - Gj) * bj * accQ[s][t] : 0.f;
    }
  }
  for (int u = tid; u < 1024; u += 256) {
    int f = u * 4; int row = f >> 6; int col = f & 63;
    float pf = __expf(Gs[row]);
    float4 q = *(float4*)&XVs[row][col];
    q.x *= pf; q.y *= pf; q.z *= pf; q.w *= pf;
    *(float4*)(Qb + f) = q;
  }
  __syncthreads();

  const int sc = tid >> 2, hh = tid & 3;
  for (int pass = 0; pass < 2; ++pass) {
    for (int u = tid; u < 1024; u += 256) {
      int f = u * 4; int row = f >> 6; int col = f & 63;
      if (pass == 0) {
        *(float4*)&XVs[row][col] = *(const float4*)(Vb + f);
      } else {
        float pp = __expf((row > 0) ? Gs[row-1] : 0.f);
        float4 k = *(float4*)&Ks[row][col];
        k.x *= pp; k.y *= pp; k.z *= pp; k.w *= pp;
        *(float4*)&XVs[row][col] = k;
      }
    }
    __syncthreads();
    for (int i = 1; i < 64; ++i) {
      float sum = 0.f;
      int jlo = hh * 16;
      int jhi = min(i, jlo + 16);
      for (int j = jlo; j < jhi; ++j) sum = fmaf(Ms[i][j], XVs[j][sc], sum);
      sum = dpp_xor1_add(sum);
      sum = dpp_xor2_add(sum);
      if (hh == 0) XVs[i][sc] -= sum;
      __syncthreads();
    }
    float* dst = (pass == 0) ? Vb : uG;
    for (int u = tid; u < 1024; u += 256) {
      int f = u * 4; int row = f >> 6; int col = f & 63;
      *(float4*)(dst + f) = *(float4*)&XVs[row][col];
    }
    __syncthreads();
  }
  #pragma unroll
  for (int s = 0; s < 4; ++s) {
    int rr = i4 + s;
    #pragma unroll
    for (int t = 0; t < 4; ++t) {
      int j = j0 + 16*t;
      Kb[rr*64 + j] = __expf(G63 - Gs[j]) * bv[j] * Ks[j][rr];
    }
  }
  if (tid == 0) plast[bhc] = __expf(G63);
}

// ---------------------------------------------------------------------------
// COMBINE (parallel, 2048 blocks): fold Att/U/WKT/errA into affine-step form.
//   Qeff   = QS - Att@U          -> Q rows (over QS)
//   O_intra= Att@errA            -> attU+0 (over Att)
//   Weff   = pl*I - WKT@U        -> K rows (over WKT)
//   WE     = WKT@errA            -> attU+4096 (over U)
// ---------------------------------------------------------------------------
__global__ __launch_bounds__(256) void combine_chunks(
    float* Kglob, float* Qglob, const float* __restrict__ VAglob,
    float* __restrict__ attU, const float* __restrict__ plast)
{
  __shared__ float Atts[64][68];
  __shared__ float Wkts[64][68];
  __shared__ float UTs[64][68];   // U transposed: UTs[r][j]
  __shared__ float ETs[64][68];   // errA transposed: ETs[n][j]
  __shared__ float QSs[4096];
  const int bhc = blockIdx.x;
  const int bh  = bhc >> 6, c = bhc & 63;
  const int tid = threadIdx.x;
  const size_t rowbase = ((size_t)bh * T_ + c * 64) * 64;
  float* Kb = Kglob + rowbase;          // WKT in, Weff out
  float* Qb = Qglob + rowbase;          // QS in, Qeff out
  const float* Vb = VAglob + rowbase;   // errA in
  float* attG = attU + (size_t)bhc * 8192;   // Att in, O_intra out
  float* uG   = attG + 4096;                 // U in, WE out
  const float pl = plast[bhc];

  for (int u = tid; u < 1024; u += 256) {
    int f = u * 4; int row = f >> 6; int col = f & 63;
    *(float4*)&Atts[row][col] = *(const float4*)(attG + f);
    *(float4*)&Wkts[row][col] = *(const float4*)(Kb + f);
    float4 uu = *(const float4*)(uG + f);
    UTs[col+0][row] = uu.x; UTs[col+1][row] = uu.y;
    UTs[col+2][row] = uu.z; UTs[col+3][row] = uu.w;
    float4 ee = *(const float4*)(Vb + f);
    ETs[col+0][row] = ee.x; ETs[col+1][row] = ee.y;
    ETs[col+2][row] = ee.z; ETs[col+3][row] = ee.w;
    *(float4*)&QSs[f] = *(const float4*)(Qb + f);
  }
  __syncthreads();

  const int c0 = tid & 15;
  const int i4 = (tid >> 4) * 4;
  float a1[4][4], a2[4][4], a3[4][4], a4[4][4];
  #pragma unroll
  for (int s = 0; s < 4; ++s)
    #pragma unroll
    for (int t = 0; t < 4; ++t) { a1[s][t]=0.f; a2[s][t]=0.f; a3[s][t]=0.f; a4[s][t]=0.f; }
  for (int jb = 0; jb < 64; jb += 4) {
    float4 at[4], wk[4], ut[4], et[4];
    #pragma unroll
    for (int s = 0; s < 4; ++s) {
      at[s] = *(float4*)&Atts[i4+s][jb];
      wk[s] = *(float4*)&Wkts[i4+s][jb];
    }
    #pragma unroll
    for (int t = 0; t < 4; ++t) {
      ut[t] = *(float4*)&UTs[c0+16*t][jb];
      et[t] = *(float4*)&ETs[c0+16*t][jb];
    }
    #pragma unroll
    for (int s = 0; s < 4; ++s)
      #pragma unroll
      for (int t = 0; t < 4; ++t) {
        a1[s][t] += dot4(at[s], ut[t]);   // Att@U
        a2[s][t] += dot4(at[s], et[t]);   // Att@errA
        a3[s][t] += dot4(wk[s], ut[t]);   // WKT@U
        a4[s][t] += dot4(wk[s], et[t]);   // WKT@errA
      }
  }
  #pragma unroll
  for (int s = 0; s < 4; ++s) {
    int i = i4 + s;
    #pragma unroll
    for (int t = 0; t < 4; ++t) {
      int j = c0 + 16*t;
      Qb[i*64 + j]   = QSs[i*64 + j] - a1[s][t];
      attG[i*64 + j] = a2[s][t];
      Kb[i*64 + j]   = ((i == j) ? pl : 0.f) - a3[s][t];
      uG[i*64 + j]   = a4[s][t];
    }
  }
}

// ---------------------------------------------------------------------------
// SERIAL state chain (32 blocks): S' = Weff@S0 + WE per chunk (64 steps).
// Inputs LDS-double-buffered; next chunk's loads issued under current compute.
// Writes S_c (transposed [n][r]) to Sg for c < 63.
// ---------------------------------------------------------------------------
__global__ __launch_bounds__(256) void scan_state(
    const float* __restrict__ Weffg,   // K rows
    const float* __restrict__ WEg,     // attU+4096, chunk stride 8192
    float* __restrict__ Sg)            // [bh*64+c][4096] transposed [n][r]
{
  __shared__ float S0T[64][68];
  __shared__ float Wf[2][64][68];
  __shared__ float WEs[2][4096];
  const int bh  = blockIdx.x;
  const int tid = threadIdx.x;
  const int n0  = tid & 15;
  const int i4  = (tid >> 4) * 4;
  for (int u = tid; u < 64*68; u += 256) ((float*)S0T)[u] = 0.f;

  const float* Wbase = Weffg + (size_t)bh * T_ * 64;
  const float* Ebase = WEg + (size_t)bh * 64 * 8192;

  float4 preW[4], preE[4];
  #pragma unroll
  for (int i = 0; i < 4; ++i) {
    preW[i] = ((const float4*)Wbase)[tid + 256*i];
    preE[i] = ((const float4*)Ebase)[tid + 256*i];
  }

  for (int c = 0; c < NCHUNK_; ++c) {
    const int cur = c & 1;
    #pragma unroll
    for (int i = 0; i < 4; ++i) {
      int f = (tid + 256*i) * 4;
      *(float4*)&Wf[cur][f>>6][f&63] = preW[i];
      *(float4*)&WEs[cur][f]         = preE[i];
    }
    __syncthreads();
    if (c + 1 < NCHUNK_) {
      const float4* Wn = (const float4*)(Wbase + (size_t)(c+1) * 4096);
      const float4* En = (const float4*)(Ebase + (size_t)(c+1) * 8192);
      #pragma unroll
      for (int i = 0; i < 4; ++i) {
        preW[i] = Wn[tid + 256*i];
        preE[i] = En[tid + 256*i];
      }
    }
    float acc[4][4];
    #pragma unroll
    for (int s = 0; s < 4; ++s)
      #pragma unroll
      for (int t = 0; t < 4; ++t) acc[s][t] = WEs[cur][(i4+s)*64 + n0 + 16*t];
    for (int jb = 0; jb < 64; jb += 4) {
      float4 ww[4], ss[4];
      #pragma unroll
      for (int s = 0; s < 4; ++s) ww[s] = *(float4*)&Wf[cur][i4+s][jb];
      #pragma unroll
      for (int t = 0; t < 4; ++t) ss[t] = *(float4*)&S0T[n0+16*t][jb];
      #pragma unroll
      for (int s = 0; s < 4; ++s)
        #pragma unroll
        for (int t = 0; t < 4; ++t) acc[s][t] += dot4(ww[s], ss[t]);
    }
    __syncthreads();
    float* Sc = Sg + (size_t)(bh*64 + c) * 4096;
    #pragma unroll
    for (int t = 0; t < 4; ++t) {
      float4 w; w.x = acc[0][t]; w.y = acc[1][t]; w.z = acc[2][t]; w.w = acc[3][t];
      *(float4*)&S0T[n0+16*t][i4] = w;
      if (c < NCHUNK_ - 1) *(float4*)&Sc[(n0+16*t)*64 + i4] = w;
    }
    __syncthreads();
  }
}

// ---------------------------------------------------------------------------
// O-FINAL (parallel, 2048 blocks): O = Qeff@S_{c-1} + O_intra -> V rows.
// ---------------------------------------------------------------------------
__global__ __launch_bounds__(256) void o_final(
    const float* __restrict__ Qeffg,   // Q rows
    const float* __restrict__ Ointra,  // attU+0, chunk stride 8192
    const float* __restrict__ Sg,      // [bh*64+c][4096] transposed [n][r]
    float* __restrict__ Oout)          // V rows
{
  __shared__ float Qs[64][68];
  __shared__ float ST[64][68];
  __shared__ float Oin[4096];
  const int bhc = blockIdx.x;
  const int bh  = bhc >> 6, c = bhc & 63;
  const int tid = threadIdx.x;
  const size_t rowbase = ((size_t)bh * T_ + c * 64) * 64;
  const float* Qb = Qeffg + rowbase;
  const float* Ag = Ointra + (size_t)bhc * 8192;
  for (int u = tid; u < 1024; u += 256) {
    int f = u * 4; int row = f >> 6; int col = f & 63;
    *(float4*)&Qs[row][col] = *(const float4*)(Qb + f);
    *(float4*)&Oin[f]       = *(const float4*)(Ag + f);
    if (c > 0) {
      *(float4*)&ST[row][col] = *(const float4*)(Sg + (size_t)(bhc-1)*4096 + f);
    }
  }
  __syncthreads();
  const int n0 = tid & 15;
  const int i4 = (tid >> 4) * 4;
  float acc[4][4];
  #pragma unroll
  for (int s = 0; s < 4; ++s)
    #pragma unroll
    for (int t = 0; t < 4; ++t) acc[s][t] = Oin[(i4+s)*64 + n0 + 16*t];
  if (c > 0) {
    for (int rb = 0; rb < 64; rb += 4) {
      float4 qe[4], st[4];
      #pragma unroll
      for (int s = 0; s < 4; ++s) qe[s] = *(float4*)&Qs[i4+s][rb];
      #pragma unroll
      for (int t = 0; t < 4; ++t) st[t] = *(float4*)&ST[n0+16*t][rb];
      #pragma unroll
      for (int s = 0; s < 4; ++s)
        #pragma unroll
        for (int t = 0; t < 4; ++t) acc[s][t] += dot4(qe[s], st[t]);
    }
  }
  float* Ob = Oout + rowbase;
  #pragma unroll
  for (int s = 0; s < 4; ++s)
    #pragma unroll
    for (int t = 0; t < 4; ++t) Ob[(i4+s)*64 + n0 + 16*t] = acc[s][t];
}

// ---------------------------------------------------------------------------
// Per-head RMSNorm + sigmoid output gate; writes [B,T,H*64].
// ---------------------------------------------------------------------------
__global__ __launch_bounds__(64) void rmsgate(const float* __restrict__ O,
    const float* __restrict__ g, const float* __restrict__ rmsw,
    float* __restrict__ outp)
{
  const int bh = blockIdx.y;
  const int b  = bh >> 4, h = bh & 15;
  const int t0 = blockIdx.x * 16;
  const int c  = threadIdx.x;
  const float rw = rmsw[h*64 + c];
  for (int tt = 0; tt < 16; ++tt) {
    const int t = t0 + tt;
    float o  = O[((size_t)bh*T_ + t)*64 + c];
    float ss = o*o;
    #pragma unroll
    for (int off = 32; off > 0; off >>= 1) ss += __shfl_xor(ss, off, 64);
    float r   = rsqrtf(ss * (1.f/64.f) + 1e-6f);
    float val = o * r * rw * g[((size_t)b*T_ + t)*D_ + h*64 + c];
    outp[((size_t)b*T_ + t)*D_ + h*64 + c] = val;
  }
}

// ---------------------------------------------------------------------------
// Workspace (floats), total ~49.1M ≈ 196 MB (proven size):
//   linbuf 8M : conv staging -> Sg (state chain) -> g
//   Qh 8M     : Q -> QS -> Qeff
//   Kk 8M     : K -> WKT -> Weff -> gated
//   Vv 8M     : V -> errA -> O
//   attU 16.78M : Att/U -> O_intra/WE ; g1 aliases start (after o_final)
//   alpha/beta/plast tail
// ---------------------------------------------------------------------------
extern "C" void kernel_launch(void* const* d_in, const int* in_sizes, int n_in,
                              void* d_out, int out_size, void* d_ws, size_t ws_size,
                              hipStream_t stream)
{
  const float* x    = (const float*)d_in[0];
  const float* Wq   = (const float*)d_in[1];
  const float* Wk   = (const float*)d_in[2];
  const float* Wv   = (const float*)d_in[3];
  const float* Wo   = (const float*)d_in[4];
  const float* Wa   = (const float*)d_in[5];
  const float* ba   = (const float*)d_in[6];
  const float* Wb   = (const float*)d_in[7];
  const float* bb   = (const float*)d_in[8];
  const float* Wgd  = (const float*)d_in[9];
  const float* Wgu  = (const float*)d_in[10];
  const float* rmsw = (const float*)d_in[11];
  const float* qcw  = (const float*)d_in[12];
  const float* qcb  = (const float*)d_in[13];
  const float* kcw  = (const float*)d_in[14];
  const float* kcb  = (const float*)d_in[15];
  const float* vcw  = (const float*)d_in[16];
  const float* vcb  = (const float*)d_in[17];

  float* ws = (float*)d_ws;
  const size_t S0sz = (size_t)8192 * 1024;
  float* linbuf = ws;
  float* Qh     = ws + S0sz;
  float* Kk     = ws + 2*S0sz;
  float* Vv     = ws + 3*S0sz;
  float* attU   = ws + 4*S0sz;
  float* alpha  = attU + (size_t)2048*8192;
  float* beta   = alpha + (size_t)BH_ * T_;
  float* plast  = beta + (size_t)BH_ * T_;

  const dim3 blk256(256);
  const dim3 gBig(8, 64);
  const dim3 gMid(4, 64);

  // projections + convs
  gemm_f32<0><<<gBig, blk256, 0, stream>>>(x, Wq, linbuf, 8192, 1024, 1024);
  conv_head<true ><<<dim3(T_/16, BH_), 64, 0, stream>>>(linbuf, qcw, qcb, Qh);
  gemm_f32<0><<<gBig, blk256, 0, stream>>>(x, Wk, linbuf, 8192, 1024, 1024);
  conv_head<true ><<<dim3(T_/16, BH_), 64, 0, stream>>>(linbuf, kcw, kcb, Kk);
  gemm_f32<0><<<gBig, blk256, 0, stream>>>(x, Wv, linbuf, 8192, 1024, 1024);
  conv_head<false><<<dim3(T_/16, BH_), 64, 0, stream>>>(linbuf, vcw, vcb, Vv);
  ab_kernel<<<8192, blk256, 0, stream>>>(x, Wa, ba, Wb, bb, alpha, beta);

  // chunked delta rule
  precompute_chunks<<<BH_ * NCHUNK_, blk256, 0, stream>>>(Kk, Qh, Vv, alpha, beta,
                                                          attU, plast);
  combine_chunks<<<BH_ * NCHUNK_, blk256, 0, stream>>>(Kk, Qh, Vv, attU, plast);
  float* Sg = linbuf;   // linbuf dead (conv staging done); g comes later
  scan_state<<<BH_, blk256, 0, stream>>>(Kk, attU + 4096, Sg);
  o_final<<<BH_ * NCHUNK_, blk256, 0, stream>>>(Qh, attU, Sg, Vv);

  // gate path (after attU/linbuf freed)
  float* g1 = attU;     // attU dead after o_final
  gemm_f32<1><<<gMid, blk256, 0, stream>>>(x, Wgd, g1, 8192, 512, 1024);
  float* g = linbuf;    // Sg dead after o_final
  gemm_f32<2><<<gBig, blk256, 0, stream>>>(g1, Wgu, g, 8192, 1024, 512);

  // epilogue
  float* gated = Kk;    // Weff dead after scan_state
  rmsgate<<<dim3(T_/16, BH_), 64, 0, stream>>>(Vv, g, rmsw, gated);
  gemm_f32<0><<<gBig, blk256, 0, stream>>>(gated, Wo, (float*)d_out, 8192, 1024, 1024);
}

// Round 8
// 1604.378 us; speedup vs baseline: 1.8099x; 1.3812x over previous
//
#include <hip/hip_runtime.h>
#include <math.h>

#define B_  2
#define T_  4096
#define D_  1024
#define H_  16
#define BH_ 32
#define NCHUNK_ 64   // T/64

typedef unsigned short u16;
typedef unsigned int   u32;
typedef __attribute__((ext_vector_type(8))) short bf16x8;   // 8 bf16 = 4 VGPR
typedef __attribute__((ext_vector_type(4))) float f32x4;

__device__ __forceinline__ float dpp_xor1_add(float v) {
  int s = __builtin_amdgcn_update_dpp(0, __float_as_int(v), 0xB1, 0xF, 0xF, true);
  return v + __int_as_float(s);
}
__device__ __forceinline__ float dpp_xor2_add(float v) {
  int s = __builtin_amdgcn_update_dpp(0, __float_as_int(v), 0x4E, 0xF, 0xF, true);
  return v + __int_as_float(s);
}
__device__ __forceinline__ float dot4(float4 a, float4 b) {
  return fmaf(a.x, b.x, fmaf(a.y, b.y, fmaf(a.z, b.z, a.w * b.w)));
}
__device__ __forceinline__ u16 f2bf(float x) {   // RNE f32->bf16
  u32 u = __float_as_uint(x);
  return (u16)((u + 0x7FFFu + ((u >> 16) & 1u)) >> 16);
}
__device__ __forceinline__ float bf2f(u16 b) { return __uint_as_float((u32)b << 16); }

// ---------------------------------------------------------------------------
// split: f32 -> (bf16 hi, bf16 lo) elementwise. n4 = count/4.
// ---------------------------------------------------------------------------
__global__ __launch_bounds__(256) void split_f32(const float* __restrict__ in,
    u16* __restrict__ hp, u16* __restrict__ lp, int n4)
{
  int i = blockIdx.x * 256 + threadIdx.x;
  const int stride = gridDim.x * 256;
  for (; i < n4; i += stride) {
    float4 v = ((const float4*)in)[i];
    ushort4 h, l;
    h.x = f2bf(v.x); l.x = f2bf(v.x - bf2f(h.x));
    h.y = f2bf(v.y); l.y = f2bf(v.y - bf2f(h.y));
    h.z = f2bf(v.z); l.z = f2bf(v.z - bf2f(h.z));
    h.w = f2bf(v.w); l.w = f2bf(v.w - bf2f(h.w));
    ((ushort4*)hp)[i] = h;
    ((ushort4*)lp)[i] = l;
  }
}

// ---------------------------------------------------------------------------
// transpose-split: W[K][N] f32 -> hT[N][K], lT[N][K] bf16.
// ---------------------------------------------------------------------------
__global__ __launch_bounds__(256) void tsplit_f32(const float* __restrict__ W,
    u16* __restrict__ hT, u16* __restrict__ lT, int K, int N)
{
  __shared__ float tile[32][33];
  const int kb = blockIdx.y * 32, nb = blockIdx.x * 32;
  const int tx = threadIdx.x & 31, ty = threadIdx.x >> 5;  // 32 x 8
  #pragma unroll
  for (int r = 0; r < 32; r += 8)
    tile[ty + r][tx] = W[(size_t)(kb + ty + r) * N + nb + tx];
  __syncthreads();
  #pragma unroll
  for (int r = 0; r < 32; r += 8) {
    float x = tile[tx][ty + r];          // = W[kb+tx][nb+ty+r]
    u16 h = f2bf(x);
    hT[(size_t)(nb + ty + r) * K + kb + tx] = h;
    lT[(size_t)(nb + ty + r) * K + kb + tx] = f2bf(x - bf2f(h));
  }
}

// ---------------------------------------------------------------------------
// Split-bf16 MFMA GEMM: C[M,N] = (Ah+Al)[M,K] @ (Bh+Bl)[K,N], f32 out.
// B pre-transposed [N][K]. BM=BN=128, BK=32, 256 thr = 4 waves (2x2 of 64x64).
// 3-term split: AhBh + AhBl + AlBh (AlBl term ~2^-18, dropped).
// LDS layout per operand: [kgroup 0..3][row 0..127][8 shorts] (16B chunks,
// linear in chunk id -> conflict-free staging writes and frag reads).
// ACT: 0 none, 1 silu, 2 sigmoid.
// ---------------------------------------------------------------------------
template<int ACT>
__global__ __launch_bounds__(256) void gemm_bf16s(
    const u16* __restrict__ Ah, const u16* __restrict__ Al,
    const u16* __restrict__ BhT, const u16* __restrict__ BlT,
    float* __restrict__ C, int M, int N, int K)
{
  __shared__ u16 LAh[4096], LAl[4096], LBh[4096], LBl[4096];
  const int tid  = threadIdx.x;
  const int lane = tid & 63;
  const int wave = tid >> 6;
  const int wm = (wave >> 1) * 64, wn = (wave & 1) * 64;
  const int bm = blockIdx.y * 128, bn = blockIdx.x * 128;
  const int l15 = lane & 15, kg = lane >> 4;
  f32x4 acc[4][4];
  #pragma unroll
  for (int i = 0; i < 4; ++i)
    #pragma unroll
    for (int j = 0; j < 4; ++j) acc[i][j] = (f32x4){0.f, 0.f, 0.f, 0.f};

  // staging: chunk c = tid (kgrp 0/1) and tid+256 (kgrp 2/3); row = tid&127
  const int r0 = tid & 127, g0 = tid >> 7;
  const size_t arow = (size_t)(bm + r0) * K;
  const size_t brow = (size_t)(bn + r0) * K;

  for (int k0 = 0; k0 < K; k0 += 32) {
    const size_t ka = arow + k0 + g0 * 8;
    const size_t kb = brow + k0 + g0 * 8;
    bf16x8 vah0 = *(const bf16x8*)(Ah + ka);
    bf16x8 vah1 = *(const bf16x8*)(Ah + ka + 16);
    bf16x8 val0 = *(const bf16x8*)(Al + ka);
    bf16x8 val1 = *(const bf16x8*)(Al + ka + 16);
    bf16x8 vbh0 = *(const bf16x8*)(BhT + kb);
    bf16x8 vbh1 = *(const bf16x8*)(BhT + kb + 16);
    bf16x8 vbl0 = *(const bf16x8*)(BlT + kb);
    bf16x8 vbl1 = *(const bf16x8*)(BlT + kb + 16);
    __syncthreads();   // previous iteration's frag reads complete
    const int s0 = (g0 * 128 + r0) * 8;
    const int s1 = ((g0 + 2) * 128 + r0) * 8;
    *(bf16x8*)&LAh[s0] = vah0;  *(bf16x8*)&LAh[s1] = vah1;
    *(bf16x8*)&LAl[s0] = val0;  *(bf16x8*)&LAl[s1] = val1;
    *(bf16x8*)&LBh[s0] = vbh0;  *(bf16x8*)&LBh[s1] = vbh1;
    *(bf16x8*)&LBl[s0] = vbl0;  *(bf16x8*)&LBl[s1] = vbl1;
    __syncthreads();   // staging visible
    bf16x8 fah[4], fal[4], fbh[4], fbl[4];
    #pragma unroll
    for (int i = 0; i < 4; ++i) {
      fah[i] = *(bf16x8*)&LAh[(kg * 128 + wm + i * 16 + l15) * 8];
      fal[i] = *(bf16x8*)&LAl[(kg * 128 + wm + i * 16 + l15) * 8];
      fbh[i] = *(bf16x8*)&LBh[(kg * 128 + wn + i * 16 + l15) * 8];
      fbl[i] = *(bf16x8*)&LBl[(kg * 128 + wn + i * 16 + l15) * 8];
    }
    #pragma unroll
    for (int i = 0; i < 4; ++i)
      #pragma unroll
      for (int j = 0; j < 4; ++j) {
        acc[i][j] = __builtin_amdgcn_mfma_f32_16x16x32_bf16(fah[i], fbh[j], acc[i][j], 0, 0, 0);
        acc[i][j] = __builtin_amdgcn_mfma_f32_16x16x32_bf16(fah[i], fbl[j], acc[i][j], 0, 0, 0);
        acc[i][j] = __builtin_amdgcn_mfma_f32_16x16x32_bf16(fal[i], fbh[j], acc[i][j], 0, 0, 0);
      }
  }
  // epilogue: C/D layout col = lane&15, row = (lane>>4)*4 + reg  [m89-verified]
  #pragma unroll
  for (int i = 0; i < 4; ++i)
    #pragma unroll
    for (int j = 0; j < 4; ++j)
      #pragma unroll
      for (int r = 0; r < 4; ++r) {
        float v = acc[i][j][r];
        if (ACT == 1)      v = v / (1.f + __expf(-v));
        else if (ACT == 2) v = 1.f / (1.f + __expf(-v));
        int row = bm + wm + i * 16 + kg * 4 + r;
        int col = bn + wn + j * 16 + l15;
        C[(size_t)row * N + col] = v;
      }
}

// ---------------------------------------------------------------------------
// Causal depthwise conv (K=4) + bias + SiLU, heads [BH,T,64], optional L2N.
// ---------------------------------------------------------------------------
template<bool L2N>
__global__ __launch_bounds__(64) void conv_head(const float* __restrict__ xin,
    const float* __restrict__ w, const float* __restrict__ bias,
    float* __restrict__ out)
{
  const int bh = blockIdx.y;
  const int b  = bh >> 4, h = bh & 15;
  const int t0 = blockIdx.x * 16;
  const int c  = threadIdx.x;
  const int ch = h*64 + c;
  const float w0 = w[ch*4+0], w1 = w[ch*4+1], w2 = w[ch*4+2], w3 = w[ch*4+3];
  const float bs = bias[ch];
  const float* xp = xin + ((size_t)b*T_ + t0)*D_ + ch;
  float xm3 = (t0 >= 3) ? xp[-3*D_] : 0.f;
  float xm2 = (t0 >= 2) ? xp[-2*D_] : 0.f;
  float xm1 = (t0 >= 1) ? xp[-1*D_] : 0.f;
  float* op = out + ((size_t)bh*T_ + t0)*64 + c;
  for (int tt = 0; tt < 16; ++tt) {
    float xc = xp[(size_t)tt * D_];
    float v  = fmaf(w0, xm3, fmaf(w1, xm2, fmaf(w2, xm1, fmaf(w3, xc, bs))));
    v = v / (1.f + __expf(-v));
    if (L2N) {
      float ss = v*v;
      #pragma unroll
      for (int off = 32; off > 0; off >>= 1) ss += __shfl_xor(ss, off, 64);
      v = v / fmaxf(sqrtf(ss), 1e-6f);
    }
    op[tt*64] = v;
    xm3 = xm2; xm2 = xm1; xm1 = xc;
  }
}

// ---------------------------------------------------------------------------
// alpha/beta gates
// ---------------------------------------------------------------------------
__global__ __launch_bounds__(256) void ab_kernel(const float* __restrict__ x,
    const float* __restrict__ Wa, const float* __restrict__ ba,
    const float* __restrict__ Wb, const float* __restrict__ bb,
    float* __restrict__ alpha, float* __restrict__ beta)
{
  __shared__ float xs[1024];
  const int rrow = blockIdx.x;
  const int b = rrow >> 12, t = rrow & 4095;
  const int tid = threadIdx.x;
  ((float4*)xs)[tid] = ((const float4*)(x + (size_t)rrow * D_))[tid];
  __syncthreads();
  const int out = tid >> 3;
  const int s   = tid & 7;
  const bool isB = out >= 16;
  const int h = out & 15;
  const float* W = isB ? Wb : Wa;
  float acc = 0.f;
  #pragma unroll 8
  for (int m = 0; m < 128; ++m) {
    int kidx = m*8 + s;
    acc = fmaf(xs[kidx], W[kidx*16 + h], acc);
  }
  acc += __shfl_xor(acc, 1, 64);
  acc += __shfl_xor(acc, 2, 64);
  acc += __shfl_xor(acc, 4, 64);
  if (s == 0) {
    float bias = isB ? bb[h] : ba[h];
    float sg = 1.f / (1.f + __expf(-(acc + bias)));
    int bh = b*16 + h;
    if (isB) beta [(size_t)bh*T_ + t] = fminf(sg, 1.0f);
    else     alpha[(size_t)bh*T_ + t] = fminf(fmaxf(sg, 0.1f), 1.0f);
  }
}

// ---------------------------------------------------------------------------
// CHUNKED DELTA RULE — precompute (validated, unchanged).
// ---------------------------------------------------------------------------
__global__ __launch_bounds__(256) void precompute_chunks(
    float* Kglob, float* Qglob, float* VAglob,
    const float* __restrict__ alpha, const float* __restrict__ beta,
    float* __restrict__ attU, float* __restrict__ plast)
{
  __shared__ float Ks[64][68];
  __shared__ float XVs[64][64];
  __shared__ float Ms[64][64];
  __shared__ float Gs[64], bv[64];
  const int bhc = blockIdx.x;
  const int bh  = bhc >> 6, c = bhc & 63;
  const int tid = threadIdx.x;
  const size_t rowbase = ((size_t)bh * T_ + c * 64) * 64;
  float* Kb = Kglob + rowbase;
  float* Qb = Qglob + rowbase;
  float* Vb = VAglob + rowbase;
  float* attG = attU + (size_t)bhc * 8192;
  float* uG   = attG + 4096;

  for (int u = tid; u < 1024; u += 256) {
    int f = u * 4; int row = f >> 6; int col = f & 63;
    *(float4*)&Ks[row][col]  = *(const float4*)(Kb + f);
    *(float4*)&XVs[row][col] = *(const float4*)(Qb + f);
  }
  if (tid < 64) {
    bv[tid] = beta[(size_t)bh*T_ + c*64 + tid];
    float xv = __logf(alpha[(size_t)bh*T_ + c*64 + tid]);
    #pragma unroll
    for (int off = 1; off < 64; off <<= 1) {
      float n = __shfl_up(xv, off, 64);
      if (tid >= off) xv += n;
    }
    Gs[tid] = xv;
  }
  __syncthreads();

  const int j0 = tid & 15;
  const int i4 = (tid >> 4) * 4;
  float accK[4][4], accQ[4][4];
  #pragma unroll
  for (int s = 0; s < 4; ++s)
    #pragma unroll
    for (int t = 0; t < 4; ++t) { accK[s][t] = 0.f; accQ[s][t] = 0.f; }
  for (int db = 0; db < 64; db += 4) {
    float4 ki[4], qi[4], kj[4];
    #pragma unroll
    for (int s = 0; s < 4; ++s) {
      ki[s] = *(float4*)&Ks[i4+s][db];
      qi[s] = *(float4*)&XVs[i4+s][db];
    }
    #pragma unroll
    for (int t = 0; t < 4; ++t) kj[t] = *(float4*)&Ks[j0+16*t][db];
    #pragma unroll
    for (int s = 0; s < 4; ++s)
      #pragma unroll
      for (int t = 0; t < 4; ++t) {
        accK[s][t] += dot4(ki[s], kj[t]);
        accQ[s][t] += dot4(qi[s], kj[t]);
      }
  }
  const float G63 = Gs[63];
  #pragma unroll
  for (int s = 0; s < 4; ++s) {
    int i = i4 + s;
    float Gi = Gs[i];
    float Gim1 = (i > 0) ? Gs[i-1] : 0.f;
    #pragma unroll
    for (int t = 0; t < 4; ++t) {
      int j = j0 + 16*t;
      float bj = bv[j], Gj = Gs[j];
      Ms[i][j] = (j < i) ? __expf(Gim1 - Gj) * bj * accK[s][t] : 0.f;
      attG[i*64 + j] = (j <= i) ? __expf(Gi - Gj) * bj * accQ[s][t] : 0.f;
    }
  }
  for (int u = tid; u < 1024; u += 256) {
    int f = u * 4; int row = f >> 6; int col = f & 63;
    float pf = __expf(Gs[row]);
    float4 q = *(float4*)&XVs[row][col];
    q.x *= pf; q.y *= pf; q.z *= pf; q.w *= pf;
    *(float4*)(Qb + f) = q;
  }
  __syncthreads();

  const int sc = tid >> 2, hh = tid & 3;
  for (int pass = 0; pass < 2; ++pass) {
    for (int u = tid; u < 1024; u += 256) {
      int f = u * 4; int row = f >> 6; int col = f & 63;
      if (pass == 0) {
        *(float4*)&XVs[row][col] = *(const float4*)(Vb + f);
      } else {
        float pp = __expf((row > 0) ? Gs[row-1] : 0.f);
        float4 k = *(float4*)&Ks[row][col];
        k.x *= pp; k.y *= pp; k.z *= pp; k.w *= pp;
        *(float4*)&XVs[row][col] = k;
      }
    }
    __syncthreads();
    for (int i = 1; i < 64; ++i) {
      float sum = 0.f;
      int jlo = hh * 16;
      int jhi = min(i, jlo + 16);
      for (int j = jlo; j < jhi; ++j) sum = fmaf(Ms[i][j], XVs[j][sc], sum);
      sum = dpp_xor1_add(sum);
      sum = dpp_xor2_add(sum);
      if (hh == 0) XVs[i][sc] -= sum;
      __syncthreads();
    }
    float* dst = (pass == 0) ? Vb : uG;
    for (int u = tid; u < 1024; u += 256) {
      int f = u * 4; int row = f >> 6; int col = f & 63;
      *(float4*)(dst + f) = *(float4*)&XVs[row][col];
    }
    __syncthreads();
  }
  #pragma unroll
  for (int s = 0; s < 4; ++s) {
    int rr = i4 + s;
    #pragma unroll
    for (int t = 0; t < 4; ++t) {
      int j = j0 + 16*t;
      Kb[rr*64 + j] = __expf(G63 - Gs[j]) * bv[j] * Ks[j][rr];
    }
  }
  if (tid == 0) plast[bhc] = __expf(G63);
}

// ---------------------------------------------------------------------------
// COMBINE (validated, unchanged): Qeff/O_intra/Weff/WE.
// ---------------------------------------------------------------------------
__global__ __launch_bounds__(256) void combine_chunks(
    float* Kglob, float* Qglob, const float* __restrict__ VAglob,
    float* __restrict__ attU, const float* __restrict__ plast)
{
  __shared__ float Atts[64][68];
  __shared__ float Wkts[64][68];
  __shared__ float UTs[64][68];
  __shared__ float ETs[64][68];
  __shared__ float QSs[4096];
  const int bhc = blockIdx.x;
  const int bh  = bhc >> 6, c = bhc & 63;
  const int tid = threadIdx.x;
  const size_t rowbase = ((size_t)bh * T_ + c * 64) * 64;
  float* Kb = Kglob + rowbase;
  float* Qb = Qglob + rowbase;
  const float* Vb = VAglob + rowbase;
  float* attG = attU + (size_t)bhc * 8192;
  float* uG   = attG + 4096;
  const float pl = plast[bhc];

  for (int u = tid; u < 1024; u += 256) {
    int f = u * 4; int row = f >> 6; int col = f & 63;
    *(float4*)&Atts[row][col] = *(const float4*)(attG + f);
    *(float4*)&Wkts[row][col] = *(const float4*)(Kb + f);
    float4 uu = *(const float4*)(uG + f);
    UTs[col+0][row] = uu.x; UTs[col+1][row] = uu.y;
    UTs[col+2][row] = uu.z; UTs[col+3][row] = uu.w;
    float4 ee = *(const float4*)(Vb + f);
    ETs[col+0][row] = ee.x; ETs[col+1][row] = ee.y;
    ETs[col+2][row] = ee.z; ETs[col+3][row] = ee.w;
    *(float4*)&QSs[f] = *(const float4*)(Qb + f);
  }
  __syncthreads();

  const int c0 = tid & 15;
  const int i4 = (tid >> 4) * 4;
  float a1[4][4], a2[4][4], a3[4][4], a4[4][4];
  #pragma unroll
  for (int s = 0; s < 4; ++s)
    #pragma unroll
    for (int t = 0; t < 4; ++t) { a1[s][t]=0.f; a2[s][t]=0.f; a3[s][t]=0.f; a4[s][t]=0.f; }
  for (int jb = 0; jb < 64; jb += 4) {
    float4 at[4], wk[4], ut[4], et[4];
    #pragma unroll
    for (int s = 0; s < 4; ++s) {
      at[s] = *(float4*)&Atts[i4+s][jb];
      wk[s] = *(float4*)&Wkts[i4+s][jb];
    }
    #pragma unroll
    for (int t = 0; t < 4; ++t) {
      ut[t] = *(float4*)&UTs[c0+16*t][jb];
      et[t] = *(float4*)&ETs[c0+16*t][jb];
    }
    #pragma unroll
    for (int s = 0; s < 4; ++s)
      #pragma unroll
      for (int t = 0; t < 4; ++t) {
        a1[s][t] += dot4(at[s], ut[t]);
        a2[s][t] += dot4(at[s], et[t]);
        a3[s][t] += dot4(wk[s], ut[t]);
        a4[s][t] += dot4(wk[s], et[t]);
      }
  }
  #pragma unroll
  for (int s = 0; s < 4; ++s) {
    int i = i4 + s;
    #pragma unroll
    for (int t = 0; t < 4; ++t) {
      int j = c0 + 16*t;
      Qb[i*64 + j]   = QSs[i*64 + j] - a1[s][t];
      attG[i*64 + j] = a2[s][t];
      Kb[i*64 + j]   = ((i == j) ? pl : 0.f) - a3[s][t];
      uG[i*64 + j]   = a4[s][t];
    }
  }
}

// ---------------------------------------------------------------------------
// SERIAL state chain (validated, unchanged).
// ---------------------------------------------------------------------------
__global__ __launch_bounds__(256) void scan_state(
    const float* __restrict__ Weffg, const float* __restrict__ WEg,
    float* __restrict__ Sg)
{
  __shared__ float S0T[64][68];
  __shared__ float Wf[2][64][68];
  __shared__ float WEs[2][4096];
  const int bh  = blockIdx.x;
  const int tid = threadIdx.x;
  const int n0  = tid & 15;
  const int i4  = (tid >> 4) * 4;
  for (int u = tid; u < 64*68; u += 256) ((float*)S0T)[u] = 0.f;

  const float* Wbase = Weffg + (size_t)bh * T_ * 64;
  const float* Ebase = WEg + (size_t)bh * 64 * 8192;

  float4 preW[4], preE[4];
  #pragma unroll
  for (int i = 0; i < 4; ++i) {
    preW[i] = ((const float4*)Wbase)[tid + 256*i];
    preE[i] = ((const float4*)Ebase)[tid + 256*i];
  }

  for (int c = 0; c < NCHUNK_; ++c) {
    const int cur = c & 1;
    #pragma unroll
    for (int i = 0; i < 4; ++i) {
      int f = (tid + 256*i) * 4;
      *(float4*)&Wf[cur][f>>6][f&63] = preW[i];
      *(float4*)&WEs[cur][f]         = preE[i];
    }
    __syncthreads();
    if (c + 1 < NCHUNK_) {
      const float4* Wn = (const float4*)(Wbase + (size_t)(c+1) * 4096);
      const float4* En = (const float4*)(Ebase + (size_t)(c+1) * 8192);
      #pragma unroll
      for (int i = 0; i < 4; ++i) {
        preW[i] = Wn[tid + 256*i];
        preE[i] = En[tid + 256*i];
      }
    }
    float acc[4][4];
    #pragma unroll
    for (int s = 0; s < 4; ++s)
      #pragma unroll
      for (int t = 0; t < 4; ++t) acc[s][t] = WEs[cur][(i4+s)*64 + n0 + 16*t];
    for (int jb = 0; jb < 64; jb += 4) {
      float4 ww[4], ss[4];
      #pragma unroll
      for (int s = 0; s < 4; ++s) ww[s] = *(float4*)&Wf[cur][i4+s][jb];
      #pragma unroll
      for (int t = 0; t < 4; ++t) ss[t] = *(float4*)&S0T[n0+16*t][jb];
      #pragma unroll
      for (int s = 0; s < 4; ++s)
        #pragma unroll
        for (int t = 0; t < 4; ++t) acc[s][t] += dot4(ww[s], ss[t]);
    }
    __syncthreads();
    float* Sc = Sg + (size_t)(bh*64 + c) * 4096;
    #pragma unroll
    for (int t = 0; t < 4; ++t) {
      float4 w; w.x = acc[0][t]; w.y = acc[1][t]; w.z = acc[2][t]; w.w = acc[3][t];
      *(float4*)&S0T[n0+16*t][i4] = w;
      if (c < NCHUNK_ - 1) *(float4*)&Sc[(n0+16*t)*64 + i4] = w;
    }
    __syncthreads();
  }
}

// ---------------------------------------------------------------------------
// O-FINAL (validated, unchanged).
// ---------------------------------------------------------------------------
__global__ __launch_bounds__(256) void o_final(
    const float* __restrict__ Qeffg, const float* __restrict__ Ointra,
    const float* __restrict__ Sg, float* __restrict__ Oout)
{
  __shared__ float Qs[64][68];
  __shared__ float ST[64][68];
  __shared__ float Oin[4096];
  const int bhc = blockIdx.x;
  const int bh  = bhc >> 6, c = bhc & 63;
  const int tid = threadIdx.x;
  const size_t rowbase = ((size_t)bh * T_ + c * 64) * 64;
  const float* Qb = Qeffg + rowbase;
  const float* Ag = Ointra + (size_t)bhc * 8192;
  for (int u = tid; u < 1024; u += 256) {
    int f = u * 4; int row = f >> 6; int col = f & 63;
    *(float4*)&Qs[row][col] = *(const float4*)(Qb + f);
    *(float4*)&Oin[f]       = *(const float4*)(Ag + f);
    if (c > 0) {
      *(float4*)&ST[row][col] = *(const float4*)(Sg + (size_t)(bhc-1)*4096 + f);
    }
  }
  __syncthreads();
  const int n0 = tid & 15;
  const int i4 = (tid >> 4) * 4;
  float acc[4][4];
  #pragma unroll
  for (int s = 0; s < 4; ++s)
    #pragma unroll
    for (int t = 0; t < 4; ++t) acc[s][t] = Oin[(i4+s)*64 + n0 + 16*t];
  if (c > 0) {
    for (int rb = 0; rb < 64; rb += 4) {
      float4 qe[4], st[4];
      #pragma unroll
      for (int s = 0; s < 4; ++s) qe[s] = *(float4*)&Qs[i4+s][rb];
      #pragma unroll
      for (int t = 0; t < 4; ++t) st[t] = *(float4*)&ST[n0+16*t][rb];
      #pragma unroll
      for (int s = 0; s < 4; ++s)
        #pragma unroll
        for (int t = 0; t < 4; ++t) acc[s][t] += dot4(qe[s], st[t]);
    }
  }
  float* Ob = Oout + rowbase;
  #pragma unroll
  for (int s = 0; s < 4; ++s)
    #pragma unroll
    for (int t = 0; t < 4; ++t) Ob[(i4+s)*64 + n0 + 16*t] = acc[s][t];
}

// ---------------------------------------------------------------------------
// Per-head RMSNorm + sigmoid output gate; writes [B,T,H*64].
// ---------------------------------------------------------------------------
__global__ __launch_bounds__(64) void rmsgate(const float* __restrict__ O,
    const float* __restrict__ g, const float* __restrict__ rmsw,
    float* __restrict__ outp)
{
  const int bh = blockIdx.y;
  const int b  = bh >> 4, h = bh & 15;
  const int t0 = blockIdx.x * 16;
  const int c  = threadIdx.x;
  const float rw = rmsw[h*64 + c];
  for (int tt = 0; tt < 16; ++tt) {
    const int t = t0 + tt;
    float o  = O[((size_t)bh*T_ + t)*64 + c];
    float ss = o*o;
    #pragma unroll
    for (int off = 32; off > 0; off >>= 1) ss += __shfl_xor(ss, off, 64);
    float r   = rsqrtf(ss * (1.f/64.f) + 1e-6f);
    float val = o * r * rw * g[((size_t)b*T_ + t)*D_ + h*64 + c];
    outp[((size_t)b*T_ + t)*D_ + h*64 + c] = val;
  }
}

// ---------------------------------------------------------------------------
// Workspace (floats), 196 MB total (proven size). bf16 buffers live inside
// attU during its dead phases:
//   early: xh/xl @attU+0..32MB, weight splits @attU+32..36MB
//   (precompute..o_final use attU as Att/U)
//   late:  x-resplit/g1h/l/wgu/g1f32/weight splits inside attU; gated split
//          inside Vv (O dead after rmsgate).
// ---------------------------------------------------------------------------
extern "C" void kernel_launch(void* const* d_in, const int* in_sizes, int n_in,
                              void* d_out, int out_size, void* d_ws, size_t ws_size,
                              hipStream_t stream)
{
  const float* x    = (const float*)d_in[0];
  const float* Wq   = (const float*)d_in[1];
  const float* Wk   = (const float*)d_in[2];
  const float* Wv   = (const float*)d_in[3];
  const float* Wo   = (const float*)d_in[4];
  const float* Wa   = (const float*)d_in[5];
  const float* ba   = (const float*)d_in[6];
  const float* Wb   = (const float*)d_in[7];
  const float* bb   = (const float*)d_in[8];
  const float* Wgd  = (const float*)d_in[9];
  const float* Wgu  = (const float*)d_in[10];
  const float* rmsw = (const float*)d_in[11];
  const float* qcw  = (const float*)d_in[12];
  const float* qcb  = (const float*)d_in[13];
  const float* kcw  = (const float*)d_in[14];
  const float* kcb  = (const float*)d_in[15];
  const float* vcw  = (const float*)d_in[16];
  const float* vcb  = (const float*)d_in[17];

  float* ws = (float*)d_ws;
  const size_t S0sz = (size_t)8192 * 1024;
  float* linbuf = ws;
  float* Qh     = ws + S0sz;
  float* Kk     = ws + 2*S0sz;
  float* Vv     = ws + 3*S0sz;
  float* attU   = ws + 4*S0sz;
  float* alpha  = attU + (size_t)2048*8192;
  float* beta   = alpha + (size_t)BH_ * T_;
  float* plast  = beta + (size_t)BH_ * T_;

  // bf16 sub-allocations inside attU (float offsets: 1M floats = 4MB)
  u16* xh  = (u16*)attU;                                  // 16MB
  u16* xl  = xh + (size_t)8192*1024;                      // +16MB
  u16* wth = (u16*)(attU + (size_t)8*1024*1024);          // attU+32MB (2MB max)
  u16* wtl = wth + (size_t)1024*1024;                     // attU+34MB

  const dim3 blk256(256);
  const dim3 gC(T_/16, BH_);
  const dim3 gG8(8, 64);    // N=1024
  const dim3 gG4(4, 64);    // N=512

  // ---- projections via split-bf16 MFMA ----
  split_f32<<<1024, blk256, 0, stream>>>(x, xh, xl, 8192*1024/4);
  tsplit_f32<<<dim3(32,32), blk256, 0, stream>>>(Wq, wth, wtl, 1024, 1024);
  gemm_bf16s<0><<<gG8, blk256, 0, stream>>>(xh, xl, wth, wtl, linbuf, 8192, 1024, 1024);
  conv_head<true ><<<gC, 64, 0, stream>>>(linbuf, qcw, qcb, Qh);
  tsplit_f32<<<dim3(32,32), blk256, 0, stream>>>(Wk, wth, wtl, 1024, 1024);
  gemm_bf16s<0><<<gG8, blk256, 0, stream>>>(xh, xl, wth, wtl, linbuf, 8192, 1024, 1024);
  conv_head<true ><<<gC, 64, 0, stream>>>(linbuf, kcw, kcb, Kk);
  tsplit_f32<<<dim3(32,32), blk256, 0, stream>>>(Wv, wth, wtl, 1024, 1024);
  gemm_bf16s<0><<<gG8, blk256, 0, stream>>>(xh, xl, wth, wtl, linbuf, 8192, 1024, 1024);
  conv_head<false><<<gC, 64, 0, stream>>>(linbuf, vcw, vcb, Vv);
  ab_kernel<<<8192, blk256, 0, stream>>>(x, Wa, ba, Wb, bb, alpha, beta);

  // ---- chunked delta rule (xh/xl/wt dead; attU reused as Att/U) ----
  precompute_chunks<<<BH_ * NCHUNK_, blk256, 0, stream>>>(Kk, Qh, Vv, alpha, beta,
                                                          attU, plast);
  combine_chunks<<<BH_ * NCHUNK_, blk256, 0, stream>>>(Kk, Qh, Vv, attU, plast);
  float* Sg = linbuf;
  scan_state<<<BH_, blk256, 0, stream>>>(Kk, attU + 4096, Sg);
  o_final<<<BH_ * NCHUNK_, blk256, 0, stream>>>(Qh, attU, Sg, Vv);

  // ---- gate path (attU dead again) ----
  split_f32<<<1024, blk256, 0, stream>>>(x, xh, xl, 8192*1024/4);
  tsplit_f32<<<dim3(16,32), blk256, 0, stream>>>(Wgd, wth, wtl, 1024, 512);
  float* g1f = attU + (size_t)9*1024*1024;   // attU+36MB, 16MB
  gemm_bf16s<1><<<gG4, blk256, 0, stream>>>(xh, xl, wth, wtl, g1f, 8192, 512, 1024);
  u16* g1h = (u16*)attU;                     // overwrites xh (dead)
  u16* g1l = g1h + (size_t)8192*512;
  split_f32<<<1024, blk256, 0, stream>>>(g1f, g1h, g1l, 8192*512/4);
  u16* wuh = (u16*)(attU + (size_t)4*1024*1024);  // attU+16MB (xl dead)
  u16* wul = wuh + (size_t)512*1024;
  tsplit_f32<<<dim3(32,16), blk256, 0, stream>>>(Wgu, wuh, wul, 512, 1024);
  gemm_bf16s<2><<<gG8, blk256, 0, stream>>>(g1h, g1l, wuh, wul, linbuf, 8192, 1024, 512);

  // ---- epilogue ----
  rmsgate<<<gC, 64, 0, stream>>>(Vv, linbuf, rmsw, Kk);   // gated f32 -> Kk
  u16* gth = (u16*)Vv;                                     // O dead
  u16* gtl = gth + (size_t)8192*1024;
  split_f32<<<1024, blk256, 0, stream>>>(Kk, gth, gtl, 8192*1024/4);
  tsplit_f32<<<dim3(32,32), blk256, 0, stream>>>(Wo, wth, wtl, 1024, 1024);
  gemm_bf16s<0><<<gG8, blk256, 0, stream>>>(gth, gtl, wth, wtl, (float*)d_out,
                                            8192, 1024, 1024);
}